// Round 6
// baseline (152.467 us; speedup 1.0000x reference)
//
#include <hip/hip_runtime.h>
#include <hip/hip_bf16.h>

// OnlineTripletLoss: B=8192, D=128, fp32 embeddings, int32 labels, scalar out.
// d2-space fused reductions; 32x32x16 bf16 MFMA; 3-buffer LDS pipeline with
// counted vmcnt (never drains to 0 mid-loop); row&15 source-pre-swizzle;
// deferred-sqi epilogue; deterministic fixed-point finalize.

#define BB 8192
#define DD 128
#define MARGIN 0.2f
#define EPS 1e-12f

#define COLS_PER_BLOCK 512
#define ROWS_PER_BLOCK 256                     // 8 waves x 32 rows
#define STAGE_COLS 64
#define NSTAGES 8                              // COLS_PER_BLOCK / STAGE_COLS
#define STAGE_SHORTS (STAGE_COLS * DD)         // 8192 shorts = 16 KB

typedef __attribute__((ext_vector_type(8))) short short8;
typedef __attribute__((ext_vector_type(16))) float f32x16;

__device__ inline unsigned short f2bf(float f) {
    __hip_bfloat16 h = __float2bfloat16(f);
    unsigned short u;
    __builtin_memcpy(&u, &h, 2);
    return u;
}

// ---- prep: bf16 copy + packed {sq,label} meta + init reduction state -------
__global__ __launch_bounds__(256) void prep_kernel(
    const float* __restrict__ x, const int* __restrict__ lab,
    unsigned short* __restrict__ xb, float2* __restrict__ meta,
    unsigned* __restrict__ hp2, unsigned* __restrict__ mn2,
    unsigned long long* __restrict__ fsum, unsigned* __restrict__ fdone) {
    int t = blockIdx.x * blockDim.x + threadIdx.x;   // 0 .. 8192*32-1
    int row = t >> 5;                                 // 32 threads per row
    const float4 v = reinterpret_cast<const float4*>(x)[t];

    union { unsigned short u[4]; uint2 w; } p;
    p.u[0] = f2bf(v.x); p.u[1] = f2bf(v.y);
    p.u[2] = f2bf(v.z); p.u[3] = f2bf(v.w);
    reinterpret_cast<uint2*>(xb)[t] = p.w;

    float s = v.x * v.x + v.y * v.y + v.z * v.z + v.w * v.w;
    #pragma unroll
    for (int m = 16; m >= 1; m >>= 1) s += __shfl_xor(s, m, 64);  // within 32-lane row group
    if ((t & 31) == 0) meta[row] = make_float2(s, __int_as_float(lab[row]));

    if (t < BB) { hp2[t] = 0u; mn2[t] = 0x7f800000u; }  // 0, +inf
    if (t == 0) { *fsum = 0ull; *fdone = 0u; }
}

// ---- main ------------------------------------------------------------------
// grid (32, 16), 512 threads = 8 waves x 32 rows = 256 rows x 512-col chunk.
// B tiles of 64 cols in a 3-buffer LDS pipeline; counted vmcnt keeps 2 stages
// in flight; compute never waits on a freshly-issued load.
__global__ __launch_bounds__(512, 4) void triplet_main(
    const unsigned short* __restrict__ xb, const float2* __restrict__ meta,
    unsigned* __restrict__ hp2, unsigned* __restrict__ mn2) {
    const int tid  = threadIdx.x;
    const int wave = tid >> 6;
    const int lane = tid & 63;
    const int l31  = lane & 31;
    const int lh1  = lane >> 5;
    const int rbase = blockIdx.x * ROWS_PER_BLOCK + wave * 32;
    const int cbase = blockIdx.y * COLS_PER_BLOCK;

    __shared__ unsigned short sb[3][STAGE_SHORTS];   // 3 x 16 KB
    __shared__ float2 smeta[COLS_PER_BLOCK];         // 4 KB

    // A fragments: 32 rows, K=128 in 8 slices (held whole kernel).
    // mfma_f32_32x32x16_bf16 A layout: row = lane&31, k = (lane>>5)*8 + i.
    short8 a[8];
    {
        const unsigned short* ar = xb + (size_t)(rbase + l31) * DD + lh1 * 8;
        #pragma unroll
        for (int s = 0; s < 8; ++s)
            a[s] = *reinterpret_cast<const short8*>(ar + s * 16);
    }

    // C/D layout: col = lane&31, row_local = (r&3) + 8*(r>>2) + 4*(lane>>5).
    // Row labels packed 4/uint (labels < 64): li4[q] byte k = label of acc r=4q+k.
    unsigned li4[4];
    float hp[16], mn[16];
    #pragma unroll
    for (int q = 0; q < 4; ++q) {
        unsigned w = 0;
        #pragma unroll
        for (int k = 0; k < 4; ++k) {
            const int rl = 8 * q + 4 * lh1 + k;
            w |= ((unsigned)__float_as_int(meta[rbase + rl].y) & 255u) << (8 * k);
        }
        li4[q] = w;
    }
    #pragma unroll
    for (int r = 0; r < 16; ++r) { hp[r] = -__builtin_inff(); mn[r] = __builtin_inff(); }

    smeta[tid] = meta[cbase + tid];   // 512 cols of {sq,label} -> LDS

    // Stage 64 cols (16 KB) into sb[buf]: 2 x 16B gload_lds per thread.
    // LDS dest linear (wave-uniform base + lane*16); global SOURCE pre-swizzled:
    // LDS(row, b) = G(row, b ^ ((row&15)<<4)).
    auto stage = [&](int g, int buf) {
        const char* src_base = (const char*)(xb + (size_t)(cbase + g * STAGE_COLS) * DD);
        #pragma unroll
        for (int p = 0; p < 2; ++p) {
            const int o   = p * 8192 + tid * 16;            // linear byte offset
            const int row = o >> 8;
            const int byt = (o & 255) ^ ((row & 15) << 4);
            const char* src = src_base + row * 256 + byt;
            char* dst = (char*)&sb[buf][0] + p * 8192 + wave * 1024;
            __builtin_amdgcn_global_load_lds(
                (const __attribute__((address_space(1))) void*)src,
                (__attribute__((address_space(3))) void*)dst, 16, 0, 0);
        }
    };

    auto compute_group = [&](int st, int gg, int buf) {
        const char* base = (const char*)&sb[buf][0];
        const int jl = gg * 32 + l31;                       // col within stage
        const int rowoff = jl * 256;
        const int swz = (jl & 15) << 4;
        f32x16 acc = {};
        short8 b[4];
        #pragma unroll
        for (int s = 0; s < 4; ++s)
            b[s] = *reinterpret_cast<const short8*>(
                base + rowoff + ((s * 32 + lh1 * 16) ^ swz));
        #pragma unroll
        for (int s = 0; s < 4; ++s)
            acc = __builtin_amdgcn_mfma_f32_32x32x16_bf16(a[s], b[s], acc, 0, 0, 0);
        #pragma unroll
        for (int s = 0; s < 4; ++s)
            b[s] = *reinterpret_cast<const short8*>(
                base + rowoff + (((s + 4) * 32 + lh1 * 16) ^ swz));
        #pragma unroll
        for (int s = 0; s < 4; ++s)
            acc = __builtin_amdgcn_mfma_f32_32x32x16_bf16(a[s + 4], b[s], acc, 0, 0, 0);

        const float2 mj = smeta[st * STAGE_COLS + jl];
        const float sqj = mj.x;
        const int   lj  = __float_as_int(mj.y);
        #pragma unroll
        for (int q = 0; q < 4; ++q) {
            const unsigned lw = li4[q];
            #pragma unroll
            for (int k = 0; k < 4; ++k) {
                const int r = q * 4 + k;
                const float d2p = fmaf(acc[r], -2.0f, sqj);  // sqj - 2*dot (sqi deferred)
                const bool eq = (int)((lw >> (8 * k)) & 255u) == lj;
                // self-pair folds into hp: its d2' ~ -sqi -> final ~0, never wins.
                hp[r] = fmaxf(hp[r], eq ? d2p : -__builtin_inff());
                mn[r] = fminf(mn[r], eq ? __builtin_inff() : d2p);
            }
        }
    };

    // ---- 3-buffer pipeline, counted vmcnt (literal immediates via macro) ---
    stage(0, 0);
    stage(1, 1);
    // Per iter ST: wait own stage-ST loads done (vmcnt<=2: only ST+1 pending),
    // barrier (all waves' ST-writes landed; ST-1 reads finished), issue ST+2
    // into buf (ST+2)%3 (safe: last read at iter ST-1), compute ST.
    #define PIPE_ITER(ST, PEND)                                            \
        asm volatile("s_waitcnt vmcnt(" #PEND ")" ::: "memory");           \
        __syncthreads();                                                   \
        if ((ST) + 2 < NSTAGES) stage((ST) + 2, ((ST) + 2) % 3);           \
        compute_group((ST), 0, (ST) % 3);                                  \
        compute_group((ST), 1, (ST) % 3);
    PIPE_ITER(0, 2)
    PIPE_ITER(1, 2)
    PIPE_ITER(2, 2)
    PIPE_ITER(3, 2)
    PIPE_ITER(4, 2)
    PIPE_ITER(5, 2)
    PIPE_ITER(6, 2)
    PIPE_ITER(7, 0)
    #undef PIPE_ITER

    // add deferred sqi; clamp hp to >=0 (exact: reference max(d*posmask) >= 0)
    #pragma unroll
    for (int r = 0; r < 16; ++r) {
        const int rl = (r & 3) + 8 * (r >> 2) + 4 * lh1;
        const float sqi = meta[rbase + rl].x;
        hp[r] = fmaxf(sqi + hp[r], 0.0f);   // -inf (no positive seen) -> 0
        mn[r] = sqi + mn[r];                // +inf stays +inf
    }
    // reduce across the 32 column-lanes (xor<32 stays within each half-wave)
    #pragma unroll
    for (int m = 1; m < 32; m <<= 1) {
        #pragma unroll
        for (int r = 0; r < 16; ++r) {
            hp[r] = fmaxf(hp[r], __shfl_xor(hp[r], m, 64));
            mn[r] = fminf(mn[r], __shfl_xor(mn[r], m, 64));
        }
    }
    if (l31 == 0) {   // lanes 0 and 32 hold the two row-halves
        #pragma unroll
        for (int r = 0; r < 16; ++r) {
            const int i = rbase + (r & 3) + 8 * (r >> 2) + 4 * lh1;
            atomicMax(&hp2[i], __float_as_uint(hp[r]));  // >=0: uint order == float order
            atomicMin(&mn2[i], __float_as_uint(mn[r]));  // >=0 or +inf
        }
    }
}

// ---- finalize: per-row loss + deterministic fixed-point mean ---------------
// hardest_negative = min_neq d (every row has negatives: 64 labels / 8192).
__device__ inline float d_of(float d2) {
    return (d2 > EPS) ? sqrtf(d2) : 0.0f;
}

__global__ __launch_bounds__(1024) void finalize_kernel(
    const unsigned* __restrict__ hp2, const unsigned* __restrict__ mn2,
    unsigned long long* __restrict__ fsum, unsigned* __restrict__ fdone,
    float* __restrict__ out) {
    const int i = blockIdx.x * 1024 + threadIdx.x;   // 8 blocks x 1024 rows
    const float hpv = d_of(__uint_as_float(hp2[i]));
    const float mnv = d_of(__uint_as_float(mn2[i]));
    float acc = fmaxf(hpv - mnv + MARGIN, 0.0f);

    #pragma unroll
    for (int m = 1; m < 64; m <<= 1) acc += __shfl_xor(acc, m, 64);
    __shared__ float ws[16];
    const int wave = threadIdx.x >> 6;
    if ((threadIdx.x & 63) == 0) ws[wave] = acc;
    __syncthreads();
    if (threadIdx.x == 0) {
        float s = 0.0f;
        #pragma unroll
        for (int w = 0; w < 16; ++w) s += ws[w];
        // deterministic: integer atomic adds are order-independent
        atomicAdd(fsum, (unsigned long long)((double)s * 4294967296.0));
        __threadfence();
        const unsigned old = atomicAdd(fdone, 1u);
        if (old == gridDim.x - 1) {
            const unsigned long long total = atomicAdd(fsum, 0ull);
            out[0] = (float)((double)total / 4294967296.0 / (double)BB);
        }
    }
}

extern "C" void kernel_launch(void* const* d_in, const int* in_sizes, int n_in,
                              void* d_out, int out_size, void* d_ws, size_t ws_size,
                              hipStream_t stream) {
    const float* x = (const float*)d_in[0];
    const int* lab = (const int*)d_in[1];
    float* out = (float*)d_out;

    char* ws = (char*)d_ws;
    unsigned short* xb = (unsigned short*)ws;                          // 2 MB
    float2* meta = (float2*)(ws + (size_t)BB * DD * 2);                // 64 KB
    unsigned* hp2 = (unsigned*)(ws + (size_t)BB * DD * 2 + BB * 8);
    unsigned* mn2 = (unsigned*)(ws + (size_t)BB * DD * 2 + BB * 12);
    unsigned long long* fsum = (unsigned long long*)(ws + (size_t)BB * DD * 2 + BB * 16);
    unsigned* fdone = (unsigned*)(ws + (size_t)BB * DD * 2 + BB * 16 + 8);

    prep_kernel<<<(BB * DD / 4) / 256, 256, 0, stream>>>(x, lab, xb, meta, hp2, mn2, fsum, fdone);
    dim3 grid(BB / ROWS_PER_BLOCK, BB / COLS_PER_BLOCK);
    triplet_main<<<grid, 512, 0, stream>>>(xb, meta, hp2, mn2);
    finalize_kernel<<<BB / 1024, 1024, 0, stream>>>(hp2, mn2, fsum, fdone, out);
}

// Round 7
// 50.178 us; speedup vs baseline: 3.0385x; 3.0385x over previous
//
#include <hip/hip_runtime.h>
#include <hip/hip_bf16.h>

// OnlineTripletLoss: B=8192, D=128, fp32 embeddings, int32 labels, scalar out.
// d2-space fused reductions; 32x32x16 bf16 MFMA; 3-buffer LDS pipeline with
// counted vmcnt (never drains to 0 mid-loop); row&15 source-pre-swizzle;
// deferred-sqi epilogue; deterministic fixed-point finalize.
// NOTE: no min-waves launch_bounds hint -- (512,4) made hipcc clamp to 64 VGPR
// and spill ~550 MB of scratch (round 6: FETCH 240 MB / WRITE 315 MB).

#define BB 8192
#define DD 128
#define MARGIN 0.2f
#define EPS 1e-12f

#define COLS_PER_BLOCK 512
#define ROWS_PER_BLOCK 256                     // 8 waves x 32 rows
#define STAGE_COLS 64
#define NSTAGES 8                              // COLS_PER_BLOCK / STAGE_COLS
#define STAGE_SHORTS (STAGE_COLS * DD)         // 8192 shorts = 16 KB

typedef __attribute__((ext_vector_type(8))) short short8;
typedef __attribute__((ext_vector_type(16))) float f32x16;

__device__ inline unsigned short f2bf(float f) {
    __hip_bfloat16 h = __float2bfloat16(f);
    unsigned short u;
    __builtin_memcpy(&u, &h, 2);
    return u;
}

// ---- prep: bf16 copy + packed {sq,label} meta + init reduction state -------
__global__ __launch_bounds__(256) void prep_kernel(
    const float* __restrict__ x, const int* __restrict__ lab,
    unsigned short* __restrict__ xb, float2* __restrict__ meta,
    unsigned* __restrict__ hp2, unsigned* __restrict__ mn2,
    unsigned long long* __restrict__ fsum, unsigned* __restrict__ fdone) {
    int t = blockIdx.x * blockDim.x + threadIdx.x;   // 0 .. 8192*32-1
    int row = t >> 5;                                 // 32 threads per row
    const float4 v = reinterpret_cast<const float4*>(x)[t];

    union { unsigned short u[4]; uint2 w; } p;
    p.u[0] = f2bf(v.x); p.u[1] = f2bf(v.y);
    p.u[2] = f2bf(v.z); p.u[3] = f2bf(v.w);
    reinterpret_cast<uint2*>(xb)[t] = p.w;

    float s = v.x * v.x + v.y * v.y + v.z * v.z + v.w * v.w;
    #pragma unroll
    for (int m = 16; m >= 1; m >>= 1) s += __shfl_xor(s, m, 64);  // within 32-lane row group
    if ((t & 31) == 0) meta[row] = make_float2(s, __int_as_float(lab[row]));

    if (t < BB) { hp2[t] = 0u; mn2[t] = 0x7f800000u; }  // 0, +inf
    if (t == 0) { *fsum = 0ull; *fdone = 0u; }
}

// ---- main ------------------------------------------------------------------
// grid (32, 16), 512 threads = 8 waves x 32 rows = 256 rows x 512-col chunk.
// B tiles of 64 cols in a 3-buffer LDS pipeline; counted vmcnt keeps 2 stages
// in flight; compute never waits on a freshly-issued load.
__global__ __launch_bounds__(512) void triplet_main(
    const unsigned short* __restrict__ xb, const float2* __restrict__ meta,
    unsigned* __restrict__ hp2, unsigned* __restrict__ mn2) {
    const int tid  = threadIdx.x;
    const int wave = tid >> 6;
    const int lane = tid & 63;
    const int l31  = lane & 31;
    const int lh1  = lane >> 5;
    const int rbase = blockIdx.x * ROWS_PER_BLOCK + wave * 32;
    const int cbase = blockIdx.y * COLS_PER_BLOCK;

    __shared__ unsigned short sb[3][STAGE_SHORTS];   // 3 x 16 KB
    __shared__ float2 smeta[COLS_PER_BLOCK];         // 4 KB

    // A fragments: 32 rows, K=128 in 8 slices (held whole kernel).
    // mfma_f32_32x32x16_bf16 A layout: row = lane&31, k = (lane>>5)*8 + i.
    short8 a[8];
    {
        const unsigned short* ar = xb + (size_t)(rbase + l31) * DD + lh1 * 8;
        #pragma unroll
        for (int s = 0; s < 8; ++s)
            a[s] = *reinterpret_cast<const short8*>(ar + s * 16);
    }

    // C/D layout: col = lane&31, row_local = (r&3) + 8*(r>>2) + 4*(lane>>5).
    // Row labels packed 4/uint (labels < 64): li4[q] byte k = label of acc r=4q+k.
    unsigned li4[4];
    float hp[16], mn[16];
    #pragma unroll
    for (int q = 0; q < 4; ++q) {
        unsigned w = 0;
        #pragma unroll
        for (int k = 0; k < 4; ++k) {
            const int rl = 8 * q + 4 * lh1 + k;
            w |= ((unsigned)__float_as_int(meta[rbase + rl].y) & 255u) << (8 * k);
        }
        li4[q] = w;
    }
    #pragma unroll
    for (int r = 0; r < 16; ++r) { hp[r] = -__builtin_inff(); mn[r] = __builtin_inff(); }

    smeta[tid] = meta[cbase + tid];   // 512 cols of {sq,label} -> LDS

    // Stage 64 cols (16 KB) into sb[buf]: 2 x 16B gload_lds per thread.
    // LDS dest linear (wave-uniform base + lane*16); global SOURCE pre-swizzled:
    // LDS(row, b) = G(row, b ^ ((row&15)<<4)).
    auto stage = [&](int g, int buf) {
        const char* src_base = (const char*)(xb + (size_t)(cbase + g * STAGE_COLS) * DD);
        #pragma unroll
        for (int p = 0; p < 2; ++p) {
            const int o   = p * 8192 + tid * 16;            // linear byte offset
            const int row = o >> 8;
            const int byt = (o & 255) ^ ((row & 15) << 4);
            const char* src = src_base + row * 256 + byt;
            char* dst = (char*)&sb[buf][0] + p * 8192 + wave * 1024;
            __builtin_amdgcn_global_load_lds(
                (const __attribute__((address_space(1))) void*)src,
                (__attribute__((address_space(3))) void*)dst, 16, 0, 0);
        }
    };

    auto compute_group = [&](int st, int gg, int buf) {
        const char* base = (const char*)&sb[buf][0];
        const int jl = gg * 32 + l31;                       // col within stage
        const int rowoff = jl * 256;
        const int swz = (jl & 15) << 4;
        f32x16 acc = {};
        short8 b[4];
        #pragma unroll
        for (int s = 0; s < 4; ++s)
            b[s] = *reinterpret_cast<const short8*>(
                base + rowoff + ((s * 32 + lh1 * 16) ^ swz));
        #pragma unroll
        for (int s = 0; s < 4; ++s)
            acc = __builtin_amdgcn_mfma_f32_32x32x16_bf16(a[s], b[s], acc, 0, 0, 0);
        #pragma unroll
        for (int s = 0; s < 4; ++s)
            b[s] = *reinterpret_cast<const short8*>(
                base + rowoff + (((s + 4) * 32 + lh1 * 16) ^ swz));
        #pragma unroll
        for (int s = 0; s < 4; ++s)
            acc = __builtin_amdgcn_mfma_f32_32x32x16_bf16(a[s + 4], b[s], acc, 0, 0, 0);

        const float2 mj = smeta[st * STAGE_COLS + jl];
        const float sqj = mj.x;
        const int   lj  = __float_as_int(mj.y);
        #pragma unroll
        for (int q = 0; q < 4; ++q) {
            const unsigned lw = li4[q];
            #pragma unroll
            for (int k = 0; k < 4; ++k) {
                const int r = q * 4 + k;
                const float d2p = fmaf(acc[r], -2.0f, sqj);  // sqj - 2*dot (sqi deferred)
                const bool eq = (int)((lw >> (8 * k)) & 255u) == lj;
                // self-pair folds into hp: its d2' ~ -sqi -> final ~0, never wins.
                hp[r] = fmaxf(hp[r], eq ? d2p : -__builtin_inff());
                mn[r] = fminf(mn[r], eq ? __builtin_inff() : d2p);
            }
        }
    };

    // ---- 3-buffer pipeline, counted vmcnt (literal immediates via macro) ---
    stage(0, 0);
    stage(1, 1);
    // Per iter ST: wait own stage-ST loads done (vmcnt<=2: only ST+1 pending),
    // barrier (all waves' ST-writes landed; ST-1 reads finished), issue ST+2
    // into buf (ST+2)%3 (safe: last read at iter ST-1), compute ST.
    #define PIPE_ITER(ST, PEND)                                            \
        asm volatile("s_waitcnt vmcnt(" #PEND ")" ::: "memory");           \
        __syncthreads();                                                   \
        if ((ST) + 2 < NSTAGES) stage((ST) + 2, ((ST) + 2) % 3);           \
        compute_group((ST), 0, (ST) % 3);                                  \
        compute_group((ST), 1, (ST) % 3);
    PIPE_ITER(0, 2)
    PIPE_ITER(1, 2)
    PIPE_ITER(2, 2)
    PIPE_ITER(3, 2)
    PIPE_ITER(4, 2)
    PIPE_ITER(5, 2)
    PIPE_ITER(6, 2)
    PIPE_ITER(7, 0)
    #undef PIPE_ITER

    // add deferred sqi; clamp hp to >=0 (exact: reference max(d*posmask) >= 0)
    #pragma unroll
    for (int r = 0; r < 16; ++r) {
        const int rl = (r & 3) + 8 * (r >> 2) + 4 * lh1;
        const float sqi = meta[rbase + rl].x;
        hp[r] = fmaxf(sqi + hp[r], 0.0f);   // -inf (no positive seen) -> 0
        mn[r] = sqi + mn[r];                // +inf stays +inf
    }
    // reduce across the 32 column-lanes (xor<32 stays within each half-wave)
    #pragma unroll
    for (int m = 1; m < 32; m <<= 1) {
        #pragma unroll
        for (int r = 0; r < 16; ++r) {
            hp[r] = fmaxf(hp[r], __shfl_xor(hp[r], m, 64));
            mn[r] = fminf(mn[r], __shfl_xor(mn[r], m, 64));
        }
    }
    if (l31 == 0) {   // lanes 0 and 32 hold the two row-halves
        #pragma unroll
        for (int r = 0; r < 16; ++r) {
            const int i = rbase + (r & 3) + 8 * (r >> 2) + 4 * lh1;
            atomicMax(&hp2[i], __float_as_uint(hp[r]));  // >=0: uint order == float order
            atomicMin(&mn2[i], __float_as_uint(mn[r]));  // >=0 or +inf
        }
    }
}

// ---- finalize: per-row loss + deterministic fixed-point mean ---------------
// hardest_negative = min_neq d (every row has negatives: 64 labels / 8192).
__device__ inline float d_of(float d2) {
    return (d2 > EPS) ? sqrtf(d2) : 0.0f;
}

__global__ __launch_bounds__(1024) void finalize_kernel(
    const unsigned* __restrict__ hp2, const unsigned* __restrict__ mn2,
    unsigned long long* __restrict__ fsum, unsigned* __restrict__ fdone,
    float* __restrict__ out) {
    const int i = blockIdx.x * 1024 + threadIdx.x;   // 8 blocks x 1024 rows
    const float hpv = d_of(__uint_as_float(hp2[i]));
    const float mnv = d_of(__uint_as_float(mn2[i]));
    float acc = fmaxf(hpv - mnv + MARGIN, 0.0f);

    #pragma unroll
    for (int m = 1; m < 64; m <<= 1) acc += __shfl_xor(acc, m, 64);
    __shared__ float ws[16];
    const int wave = threadIdx.x >> 6;
    if ((threadIdx.x & 63) == 0) ws[wave] = acc;
    __syncthreads();
    if (threadIdx.x == 0) {
        float s = 0.0f;
        #pragma unroll
        for (int w = 0; w < 16; ++w) s += ws[w];
        // deterministic: integer atomic adds are order-independent
        atomicAdd(fsum, (unsigned long long)((double)s * 4294967296.0));
        __threadfence();
        const unsigned old = atomicAdd(fdone, 1u);
        if (old == gridDim.x - 1) {
            const unsigned long long total = atomicAdd(fsum, 0ull);
            out[0] = (float)((double)total / 4294967296.0 / (double)BB);
        }
    }
}

extern "C" void kernel_launch(void* const* d_in, const int* in_sizes, int n_in,
                              void* d_out, int out_size, void* d_ws, size_t ws_size,
                              hipStream_t stream) {
    const float* x = (const float*)d_in[0];
    const int* lab = (const int*)d_in[1];
    float* out = (float*)d_out;

    char* ws = (char*)d_ws;
    unsigned short* xb = (unsigned short*)ws;                          // 2 MB
    float2* meta = (float2*)(ws + (size_t)BB * DD * 2);                // 64 KB
    unsigned* hp2 = (unsigned*)(ws + (size_t)BB * DD * 2 + BB * 8);
    unsigned* mn2 = (unsigned*)(ws + (size_t)BB * DD * 2 + BB * 12);
    unsigned long long* fsum = (unsigned long long*)(ws + (size_t)BB * DD * 2 + BB * 16);
    unsigned* fdone = (unsigned*)(ws + (size_t)BB * DD * 2 + BB * 16 + 8);

    prep_kernel<<<(BB * DD / 4) / 256, 256, 0, stream>>>(x, lab, xb, meta, hp2, mn2, fsum, fdone);
    dim3 grid(BB / ROWS_PER_BLOCK, BB / COLS_PER_BLOCK);
    triplet_main<<<grid, 512, 0, stream>>>(xb, meta, hp2, mn2);
    finalize_kernel<<<BB / 1024, 1024, 0, stream>>>(hp2, mn2, fsum, fdone, out);
}